// Round 1
// baseline (1079.226 us; speedup 1.0000x reference)
//
#include <hip/hip_runtime.h>
#include <hip/hip_bf16.h>

typedef __attribute__((ext_vector_type(8))) short bf16x8;
typedef __attribute__((ext_vector_type(4))) float f32x4;

constexpr int N_ = 4096, D_ = 512, C_ = 50000;
constexpr float S_ = 30.0f, M_ = 0.4f, EPS_ = 1e-7f;

__device__ inline ushort f2bf(float f) {
  // round-to-nearest-even fp32 -> bf16 (inputs are normal floats, no NaN path)
  unsigned u = __builtin_bit_cast(unsigned, f);
  u += 0x7fffu + ((u >> 16) & 1u);
  return (ushort)(u >> 16);
}

// ---------------- 1) row L2-normalize x -> bf16 ----------------
__global__ __launch_bounds__(256) void norm_kernel(const float* __restrict__ x,
                                                   ushort* __restrict__ xnb) {
  const int wid = threadIdx.x >> 6;
  const int lane = threadIdx.x & 63;
  const int row = blockIdx.x * 4 + wid;            // 4 rows per block (1 wave/row)
  const float4* xr = reinterpret_cast<const float4*>(x + (size_t)row * D_);
  float4 a = xr[lane * 2];
  float4 b = xr[lane * 2 + 1];
  float ss = a.x * a.x + a.y * a.y + a.z * a.z + a.w * a.w +
             b.x * b.x + b.y * b.y + b.z * b.z + b.w * b.w;
#pragma unroll
  for (int m = 1; m < 64; m <<= 1) ss += __shfl_xor(ss, m);
  const float inv = 1.0f / sqrtf(ss);
  union { ushort u[8]; uint4 v; } pk;
  pk.u[0] = f2bf(a.x * inv); pk.u[1] = f2bf(a.y * inv);
  pk.u[2] = f2bf(a.z * inv); pk.u[3] = f2bf(a.w * inv);
  pk.u[4] = f2bf(b.x * inv); pk.u[5] = f2bf(b.y * inv);
  pk.u[6] = f2bf(b.z * inv); pk.u[7] = f2bf(b.w * inv);
  reinterpret_cast<uint4*>(xnb + (size_t)row * D_)[lane] = pk.v;
}

// ---------------- 2) fused GEMM + exp-sum + target extract ----------------
// grid = (32 row tiles, 391 col tiles), block = 256 (4 waves as 2x2 of 64x64)
__global__ __launch_bounds__(256) void gemm_kernel(
    const ushort* __restrict__ A,         // xn bf16 [N][D]
    const float* __restrict__ W,          // [C][D] fp32
    const int* __restrict__ target,       // [N]
    float* __restrict__ row_sum,          // [N] accum exp(S*logit) over all c<C
    float* __restrict__ tgt_logit) {      // [N]
  constexpr int BM = 128, BN = 128, BK = 64;
  __shared__ char As[BM * BK * 2];        // 16 KB, XOR-swizzled [r][kb^((r&7)<<4)]
  __shared__ char Bs[BN * BK * 2];        // 16 KB, XOR-swizzled [c][kb^((c&7)<<4)]
  __shared__ int tgt_s[BM];

  const int t = threadIdx.x;
  const int lane = t & 63, wid = t >> 6;
  const int wr = wid >> 1, wc = wid & 1;
  const int row0 = blockIdx.x * BM;
  const int col0 = blockIdx.y * BN;

  if (t < BM) tgt_s[t] = target[row0 + t];

  f32x4 acc[4][4] = {};

  for (int kt = 0; kt < D_ / BK; ++kt) {
    __syncthreads();
    // ---- stage A: 16 KB, 4 x 16B per thread, swizzled ds_write_b128 ----
#pragma unroll
    for (int i = 0; i < 4; ++i) {
      const int L = i * 4096 + t * 16;
      const int r = L >> 7, kb = L & 127;
      const char* gsrc = reinterpret_cast<const char*>(A) +
                         (size_t)(row0 + r) * (D_ * 2) + kt * (BK * 2) + kb;
      uint4 v = *reinterpret_cast<const uint4*>(gsrc);
      *reinterpret_cast<uint4*>(As + r * 128 + (kb ^ ((r & 7) << 4))) = v;
    }
    // ---- stage B: 32 KB fp32 -> 16 KB bf16, 8 x float4 per thread ----
#pragma unroll
    for (int j = 0; j < 8; ++j) {
      const int flat = j * 256 + t;        // float4 slot id, 16 per W row
      const int c = flat >> 4, kq = flat & 15;
      const int gc = col0 + c;
      float4 v = make_float4(0.f, 0.f, 0.f, 0.f);
      if (gc < C_)
        v = *reinterpret_cast<const float4*>(W + (size_t)gc * D_ + kt * BK + kq * 4);
      ushort4 h;
      h.x = f2bf(v.x); h.y = f2bf(v.y); h.z = f2bf(v.z); h.w = f2bf(v.w);
      const int kb = kq * 8;
      *reinterpret_cast<ushort4*>(Bs + c * 128 + (kb ^ ((c & 7) << 4))) = h;
    }
    __syncthreads();
    // ---- MFMA: 2 k-halves x 4x4 fragments ----
#pragma unroll
    for (int h = 0; h < 2; ++h) {
      const int kbh = h * 64 + ((lane >> 4) << 4);  // byte offset along K
      bf16x8 af[4], bfr[4];
#pragma unroll
      for (int m = 0; m < 4; ++m) {
        const int r = wr * 64 + m * 16 + (lane & 15);
        af[m] = *reinterpret_cast<const bf16x8*>(As + r * 128 + (kbh ^ ((r & 7) << 4)));
      }
#pragma unroll
      for (int n = 0; n < 4; ++n) {
        const int c = wc * 64 + n * 16 + (lane & 15);
        bfr[n] = *reinterpret_cast<const bf16x8*>(Bs + c * 128 + (kbh ^ ((c & 7) << 4)));
      }
#pragma unroll
      for (int m = 0; m < 4; ++m)
#pragma unroll
        for (int n = 0; n < 4; ++n)
          acc[m][n] = __builtin_amdgcn_mfma_f32_16x16x32_bf16(af[m], bfr[n], acc[m][n], 0, 0, 0);
    }
  }

  // ---- epilogue: exp-sum per row + target extraction ----
  // C/D layout: col = lane&15, row = (lane>>4)*4 + reg
#pragma unroll
  for (int m = 0; m < 4; ++m) {
#pragma unroll
    for (int j = 0; j < 4; ++j) {
      const int lr = wr * 64 + m * 16 + ((lane >> 4) << 2) + j;
      const int grow = row0 + lr;
      const int trow = tgt_s[lr];
      float s = 0.f;
#pragma unroll
      for (int n = 0; n < 4; ++n) {
        const int gcol = col0 + wc * 64 + n * 16 + (lane & 15);
        const float v = acc[m][n][j];
        if (gcol < C_) s += __expf(S_ * v);
        if (gcol == trow) tgt_logit[grow] = v;
      }
      s += __shfl_xor(s, 1); s += __shfl_xor(s, 2);
      s += __shfl_xor(s, 4); s += __shfl_xor(s, 8);
      if ((lane & 15) == 0) atomicAdd(&row_sum[grow], s);
    }
  }
}

// ---------------- 3) final arcface loss ----------------
__global__ __launch_bounds__(256) void loss_kernel(const float* __restrict__ row_sum,
                                                   const float* __restrict__ tgt_logit,
                                                   float* __restrict__ out) {
  __shared__ float red[4];
  float acc = 0.f;
  for (int i = threadIdx.x; i < N_; i += 256) {
    const float tv = tgt_logit[i];
    const float tc = fminf(fmaxf(tv, -1.0f + EPS_), 1.0f - EPS_);
    const float num = S_ * cosf(acosf(tc) + M_);
    const float excl = row_sum[i] - __expf(S_ * tv);  // drop target term
    const float den = __expf(num) + excl;
    acc += num - logf(den);
  }
#pragma unroll
  for (int m = 1; m < 64; m <<= 1) acc += __shfl_xor(acc, m);
  if ((threadIdx.x & 63) == 0) red[threadIdx.x >> 6] = acc;
  __syncthreads();
  if (threadIdx.x == 0) out[0] = -(red[0] + red[1] + red[2] + red[3]) / (float)N_;
}

extern "C" void kernel_launch(void* const* d_in, const int* in_sizes, int n_in,
                              void* d_out, int out_size, void* d_ws, size_t ws_size,
                              hipStream_t stream) {
  const float* x = (const float*)d_in[0];
  const float* W = (const float*)d_in[1];
  const int* target = (const int*)d_in[2];
  float* out = (float*)d_out;

  float* row_sum = (float*)d_ws;                 // [4096]
  float* tgt_logit = row_sum + N_;               // [4096]
  ushort* xnb = (ushort*)(row_sum + 2 * N_);     // bf16 [4096][512] = 4 MB

  hipMemsetAsync(d_ws, 0, 2 * N_ * sizeof(float), stream);
  norm_kernel<<<N_ / 4, 256, 0, stream>>>(x, xnb);
  gemm_kernel<<<dim3(N_ / 128, (C_ + 127) / 128), 256, 0, stream>>>(
      xnb, (const float*)d_in[1], target, row_sum, tgt_logit);
  loss_kernel<<<1, 256, 0, stream>>>(row_sum, tgt_logit, out);
}

// Round 2
// 524.071 us; speedup vs baseline: 2.0593x; 2.0593x over previous
//
#include <hip/hip_runtime.h>
#include <hip/hip_bf16.h>

typedef __attribute__((ext_vector_type(8))) short bf16x8;
typedef __attribute__((ext_vector_type(4))) float f32x4;
typedef __attribute__((address_space(1))) const void glob_cv;
typedef __attribute__((address_space(3))) void lds_v;

constexpr int N_ = 4096, D_ = 512, C_ = 50000;
constexpr float S_ = 30.0f, M_ = 0.4f, EPS_ = 1e-7f;

__device__ inline ushort f2bf(float f) {
  // round-to-nearest-even fp32 -> bf16
  unsigned u = __builtin_bit_cast(unsigned, f);
  u += 0x7fffu + ((u >> 16) & 1u);
  return (ushort)(u >> 16);
}

// ---------------- 0) convert W fp32 -> bf16 (one pass) ----------------
__global__ __launch_bounds__(256) void convw_kernel(const float* __restrict__ W,
                                                    ushort* __restrict__ Wb) {
  const long total = (long)C_ * D_ / 8;
  const long stride = (long)gridDim.x * 256;
  for (long k = (long)blockIdx.x * 256 + threadIdx.x; k < total; k += stride) {
    float4 a = reinterpret_cast<const float4*>(W)[2 * k];
    float4 b = reinterpret_cast<const float4*>(W)[2 * k + 1];
    union { ushort u[8]; uint4 v; } pk;
    pk.u[0] = f2bf(a.x); pk.u[1] = f2bf(a.y); pk.u[2] = f2bf(a.z); pk.u[3] = f2bf(a.w);
    pk.u[4] = f2bf(b.x); pk.u[5] = f2bf(b.y); pk.u[6] = f2bf(b.z); pk.u[7] = f2bf(b.w);
    reinterpret_cast<uint4*>(Wb)[k] = pk.v;
  }
}

// ---------------- 1) row L2-normalize x -> bf16 ----------------
__global__ __launch_bounds__(256) void norm_kernel(const float* __restrict__ x,
                                                   ushort* __restrict__ xnb) {
  const int wid = threadIdx.x >> 6;
  const int lane = threadIdx.x & 63;
  const int row = blockIdx.x * 4 + wid;
  const float4* xr = reinterpret_cast<const float4*>(x + (size_t)row * D_);
  float4 a = xr[lane * 2];
  float4 b = xr[lane * 2 + 1];
  float ss = a.x * a.x + a.y * a.y + a.z * a.z + a.w * a.w +
             b.x * b.x + b.y * b.y + b.z * b.z + b.w * b.w;
#pragma unroll
  for (int m = 1; m < 64; m <<= 1) ss += __shfl_xor(ss, m);
  const float inv = 1.0f / sqrtf(ss);
  union { ushort u[8]; uint4 v; } pk;
  pk.u[0] = f2bf(a.x * inv); pk.u[1] = f2bf(a.y * inv);
  pk.u[2] = f2bf(a.z * inv); pk.u[3] = f2bf(a.w * inv);
  pk.u[4] = f2bf(b.x * inv); pk.u[5] = f2bf(b.y * inv);
  pk.u[6] = f2bf(b.z * inv); pk.u[7] = f2bf(b.w * inv);
  reinterpret_cast<uint4*>(xnb + (size_t)row * D_)[lane] = pk.v;
}

// ---------------- 2a) fast GEMM: bf16 A,B; global_load_lds staging ----------------
// m97 structure: 128x128x64 tile, 4 waves (2x2 of 64x64), single-buffer LDS,
// linear LDS dest + XOR-swizzled global source + swizzled ds_read (rule #21).
__global__ __launch_bounds__(256) void gemm_fast(
    const ushort* __restrict__ A,         // xn bf16 [N][D]
    const ushort* __restrict__ Wb,        // bf16 [C][D]
    const int* __restrict__ target,
    float* __restrict__ row_sum,
    float* __restrict__ tgt_logit) {
  __shared__ char As[16384];   // [r 0..127][128 B], LDS[r][b] = A-row byte (b ^ ((r&7)<<4))
  __shared__ char Bs[16384];
  __shared__ int tgt_s[128];

  const int t = threadIdx.x, lane = t & 63, wid = t >> 6;
  const int wr = wid >> 1, wc = wid & 1;
  const int row0 = blockIdx.x * 128, col0 = blockIdx.y * 128;
  if (t < 128) tgt_s[t] = target[row0 + t];

  // staging geometry: chunk q covers rows q*8..q*8+7; lane l -> row q*8+(l>>3),
  // LDS byte-in-row (l&7)*16; global element offset swizzled so LDS ends up
  // holding byte (b ^ ((r&7)<<4)), with r&7 == l>>3.
  const int rsub = lane >> 3;
  const int kel = ((lane & 7) ^ rsub) << 3;   // element offset (bf16) within the 64-elem K-slab

  f32x4 acc[4][4] = {};

  for (int kt = 0; kt < D_ / 64; ++kt) {
    __syncthreads();
#pragma unroll
    for (int i = 0; i < 4; ++i) {
      const int q = wid * 4 + i;
      const int r = q * 8 + rsub;
      const ushort* srcA = A + (size_t)(row0 + r) * D_ + kt * 64 + kel;
      __builtin_amdgcn_global_load_lds((glob_cv*)srcA, (lds_v*)(As + q * 1024), 16, 0, 0);
      const int gc = col0 + r;
      const ushort* srcB = Wb + (size_t)(gc < C_ ? gc : 0) * D_ + kt * 64 + kel;
      __builtin_amdgcn_global_load_lds((glob_cv*)srcB, (lds_v*)(Bs + q * 1024), 16, 0, 0);
    }
    __syncthreads();
#pragma unroll
    for (int h = 0; h < 2; ++h) {
      const int kbh = h * 64 + ((lane >> 4) << 4);   // byte offset along K
      const int swz = (lane & 7) << 4;
      bf16x8 af[4], bfr[4];
#pragma unroll
      for (int m = 0; m < 4; ++m) {
        const int r = wr * 64 + m * 16 + (lane & 15);
        af[m] = *reinterpret_cast<const bf16x8*>(As + r * 128 + (kbh ^ swz));
      }
#pragma unroll
      for (int n = 0; n < 4; ++n) {
        const int c = wc * 64 + n * 16 + (lane & 15);
        bfr[n] = *reinterpret_cast<const bf16x8*>(Bs + c * 128 + (kbh ^ swz));
      }
#pragma unroll
      for (int m = 0; m < 4; ++m)
#pragma unroll
        for (int n = 0; n < 4; ++n)
          acc[m][n] = __builtin_amdgcn_mfma_f32_16x16x32_bf16(af[m], bfr[n], acc[m][n], 0, 0, 0);
    }
  }

  // epilogue: exp-sum per row + target extraction. C/D: col=lane&15, row=(lane>>4)*4+reg
#pragma unroll
  for (int m = 0; m < 4; ++m) {
#pragma unroll
    for (int j = 0; j < 4; ++j) {
      const int lr = wr * 64 + m * 16 + ((lane >> 4) << 2) + j;
      const int grow = row0 + lr;
      const int trow = tgt_s[lr];
      float s = 0.f;
#pragma unroll
      for (int n = 0; n < 4; ++n) {
        const int gcol = col0 + wc * 64 + n * 16 + (lane & 15);
        const float v = acc[m][n][j];
        if (gcol < C_) s += __expf(S_ * v);
        if (gcol == trow) tgt_logit[grow] = v;
      }
      s += __shfl_xor(s, 1); s += __shfl_xor(s, 2);
      s += __shfl_xor(s, 4); s += __shfl_xor(s, 8);
      if ((lane & 15) == 0) atomicAdd(&row_sum[grow], s);
    }
  }
}

// ---------------- 2b) fallback GEMM (round-1 path, fp32 W in-loop convert) ----------------
__global__ __launch_bounds__(256) void gemm_kernel(
    const ushort* __restrict__ A, const float* __restrict__ W,
    const int* __restrict__ target, float* __restrict__ row_sum,
    float* __restrict__ tgt_logit) {
  constexpr int BM = 128, BN = 128, BK = 64;
  __shared__ char As[BM * BK * 2];
  __shared__ char Bs[BN * BK * 2];
  __shared__ int tgt_s[BM];
  const int t = threadIdx.x;
  const int lane = t & 63, wid = t >> 6;
  const int wr = wid >> 1, wc = wid & 1;
  const int row0 = blockIdx.x * BM;
  const int col0 = blockIdx.y * BN;
  if (t < BM) tgt_s[t] = target[row0 + t];
  f32x4 acc[4][4] = {};
  for (int kt = 0; kt < D_ / BK; ++kt) {
    __syncthreads();
#pragma unroll
    for (int i = 0; i < 4; ++i) {
      const int L = i * 4096 + t * 16;
      const int r = L >> 7, kb = L & 127;
      const char* gsrc = reinterpret_cast<const char*>(A) +
                         (size_t)(row0 + r) * (D_ * 2) + kt * (BK * 2) + kb;
      uint4 v = *reinterpret_cast<const uint4*>(gsrc);
      *reinterpret_cast<uint4*>(As + r * 128 + (kb ^ ((r & 7) << 4))) = v;
    }
#pragma unroll
    for (int j = 0; j < 8; ++j) {
      const int flat = j * 256 + t;
      const int c = flat >> 4, kq = flat & 15;
      const int gc = col0 + c;
      float4 v = make_float4(0.f, 0.f, 0.f, 0.f);
      if (gc < C_)
        v = *reinterpret_cast<const float4*>(W + (size_t)gc * D_ + kt * BK + kq * 4);
      ushort4 h;
      h.x = f2bf(v.x); h.y = f2bf(v.y); h.z = f2bf(v.z); h.w = f2bf(v.w);
      const int kb = kq * 8;
      *reinterpret_cast<ushort4*>(Bs + c * 128 + (kb ^ ((c & 7) << 4))) = h;
    }
    __syncthreads();
#pragma unroll
    for (int h = 0; h < 2; ++h) {
      const int kbh = h * 64 + ((lane >> 4) << 4);
      bf16x8 af[4], bfr[4];
#pragma unroll
      for (int m = 0; m < 4; ++m) {
        const int r = wr * 64 + m * 16 + (lane & 15);
        af[m] = *reinterpret_cast<const bf16x8*>(As + r * 128 + (kbh ^ ((r & 7) << 4)));
      }
#pragma unroll
      for (int n = 0; n < 4; ++n) {
        const int c = wc * 64 + n * 16 + (lane & 15);
        bfr[n] = *reinterpret_cast<const bf16x8*>(Bs + c * 128 + (kbh ^ ((c & 7) << 4)));
      }
#pragma unroll
      for (int m = 0; m < 4; ++m)
#pragma unroll
        for (int n = 0; n < 4; ++n)
          acc[m][n] = __builtin_amdgcn_mfma_f32_16x16x32_bf16(af[m], bfr[n], acc[m][n], 0, 0, 0);
    }
  }
#pragma unroll
  for (int m = 0; m < 4; ++m) {
#pragma unroll
    for (int j = 0; j < 4; ++j) {
      const int lr = wr * 64 + m * 16 + ((lane >> 4) << 2) + j;
      const int grow = row0 + lr;
      const int trow = tgt_s[lr];
      float s = 0.f;
#pragma unroll
      for (int n = 0; n < 4; ++n) {
        const int gcol = col0 + wc * 64 + n * 16 + (lane & 15);
        const float v = acc[m][n][j];
        if (gcol < C_) s += __expf(S_ * v);
        if (gcol == trow) tgt_logit[grow] = v;
      }
      s += __shfl_xor(s, 1); s += __shfl_xor(s, 2);
      s += __shfl_xor(s, 4); s += __shfl_xor(s, 8);
      if ((lane & 15) == 0) atomicAdd(&row_sum[grow], s);
    }
  }
}

// ---------------- 3) final arcface loss ----------------
__global__ __launch_bounds__(256) void loss_kernel(const float* __restrict__ row_sum,
                                                   const float* __restrict__ tgt_logit,
                                                   float* __restrict__ out) {
  __shared__ float red[4];
  float acc = 0.f;
  for (int i = threadIdx.x; i < N_; i += 256) {
    const float tv = tgt_logit[i];
    const float tc = fminf(fmaxf(tv, -1.0f + EPS_), 1.0f - EPS_);
    const float num = S_ * cosf(acosf(tc) + M_);
    const float excl = row_sum[i] - __expf(S_ * tv);
    const float den = __expf(num) + excl;
    acc += num - logf(den);
  }
#pragma unroll
  for (int m = 1; m < 64; m <<= 1) acc += __shfl_xor(acc, m);
  if ((threadIdx.x & 63) == 0) red[threadIdx.x >> 6] = acc;
  __syncthreads();
  if (threadIdx.x == 0) out[0] = -(red[0] + red[1] + red[2] + red[3]) / (float)N_;
}

extern "C" void kernel_launch(void* const* d_in, const int* in_sizes, int n_in,
                              void* d_out, int out_size, void* d_ws, size_t ws_size,
                              hipStream_t stream) {
  const float* x = (const float*)d_in[0];
  const float* W = (const float*)d_in[1];
  const int* target = (const int*)d_in[2];
  float* out = (float*)d_out;

  float* row_sum = (float*)d_ws;                     // [4096]
  float* tgt_logit = row_sum + N_;                   // [4096]
  ushort* xnb = (ushort*)(row_sum + 2 * N_);         // bf16 [4096][512] = 4 MB
  ushort* Wb = xnb + (size_t)N_ * D_;                // bf16 [50000][512] = 51.2 MB

  const size_t need = 2 * N_ * sizeof(float) + (size_t)N_ * D_ * 2 + (size_t)C_ * D_ * 2;

  hipMemsetAsync(d_ws, 0, 2 * N_ * sizeof(float), stream);
  norm_kernel<<<N_ / 4, 256, 0, stream>>>(x, xnb);
  if (ws_size >= need) {
    convw_kernel<<<2048, 256, 0, stream>>>(W, Wb);
    gemm_fast<<<dim3(N_ / 128, (C_ + 127) / 128), 256, 0, stream>>>(
        xnb, Wb, target, row_sum, tgt_logit);
  } else {
    gemm_kernel<<<dim3(N_ / 128, (C_ + 127) / 128), 256, 0, stream>>>(
        xnb, W, target, row_sum, tgt_logit);
  }
  loss_kernel<<<1, 256, 0, stream>>>(row_sum, tgt_logit, out);
}

// Round 4
// 488.445 us; speedup vs baseline: 2.2095x; 1.0729x over previous
//
#include <hip/hip_runtime.h>
#include <hip/hip_bf16.h>

typedef __attribute__((ext_vector_type(8))) short bf16x8;
typedef __attribute__((ext_vector_type(4))) float f32x4;
typedef __attribute__((address_space(1))) const void glob_cv;
typedef __attribute__((address_space(3))) void lds_v;

constexpr int N_ = 4096, D_ = 512, C_ = 50000;
constexpr float S_ = 30.0f, M_ = 0.4f, EPS_ = 1e-7f;

#define WAITVM(N) asm volatile("s_waitcnt vmcnt(" #N ")" ::: "memory")

__device__ inline ushort f2bf(float f) {
  unsigned u = __builtin_bit_cast(unsigned, f);
  u += 0x7fffu + ((u >> 16) & 1u);
  return (ushort)(u >> 16);
}

// ---------------- 0) convert W fp32 -> bf16 (one pass) ----------------
__global__ __launch_bounds__(256) void convw_kernel(const float* __restrict__ W,
                                                    ushort* __restrict__ Wb) {
  const long total = (long)C_ * D_ / 8;
  const long stride = (long)gridDim.x * 256;
  for (long k = (long)blockIdx.x * 256 + threadIdx.x; k < total; k += stride) {
    float4 a = reinterpret_cast<const float4*>(W)[2 * k];
    float4 b = reinterpret_cast<const float4*>(W)[2 * k + 1];
    union { ushort u[8]; uint4 v; } pk;
    pk.u[0] = f2bf(a.x); pk.u[1] = f2bf(a.y); pk.u[2] = f2bf(a.z); pk.u[3] = f2bf(a.w);
    pk.u[4] = f2bf(b.x); pk.u[5] = f2bf(b.y); pk.u[6] = f2bf(b.z); pk.u[7] = f2bf(b.w);
    reinterpret_cast<uint4*>(Wb)[k] = pk.v;
  }
}

// ---------------- 1) row L2-normalize x -> bf16 ----------------
__global__ __launch_bounds__(256) void norm_kernel(const float* __restrict__ x,
                                                   ushort* __restrict__ xnb) {
  const int wid = threadIdx.x >> 6;
  const int lane = threadIdx.x & 63;
  const int row = blockIdx.x * 4 + wid;
  const float4* xr = reinterpret_cast<const float4*>(x + (size_t)row * D_);
  float4 a = xr[lane * 2];
  float4 b = xr[lane * 2 + 1];
  float ss = a.x * a.x + a.y * a.y + a.z * a.z + a.w * a.w +
             b.x * b.x + b.y * b.y + b.z * b.z + b.w * b.w;
#pragma unroll
  for (int m = 1; m < 64; m <<= 1) ss += __shfl_xor(ss, m);
  const float inv = 1.0f / sqrtf(ss);
  union { ushort u[8]; uint4 v; } pk;
  pk.u[0] = f2bf(a.x * inv); pk.u[1] = f2bf(a.y * inv);
  pk.u[2] = f2bf(a.z * inv); pk.u[3] = f2bf(a.w * inv);
  pk.u[4] = f2bf(b.x * inv); pk.u[5] = f2bf(b.y * inv);
  pk.u[6] = f2bf(b.z * inv); pk.u[7] = f2bf(b.w * inv);
  reinterpret_cast<uint4*>(xnb + (size_t)row * D_)[lane] = pk.v;
}

// ---------------- 2a) deep-pipelined GEMM ----------------
// BM=256, BN=128, BK=64; 512 threads = 8 waves as 4(M)x2(N), 64x64 wave tiles.
// Triple-buffered LDS (144 KB), prefetch distance 2: while computing K-tile t,
// stage t+2 into buf[(t+2)%3] (never an active read buffer -> race-free).
// Counted s_waitcnt vmcnt(12/6/0): tile t's 6 loads (issued at t-2) are the
// oldest outstanding; the 2 newer tiles' 12 loads stay in flight.
__global__ __launch_bounds__(512, 2) void gemm_deep(
    const ushort* __restrict__ A,         // xn bf16 [N][D]
    const ushort* __restrict__ Wb,        // bf16 [C][D]
    const int* __restrict__ target,
    float* __restrict__ row_sum,
    float* __restrict__ tgt_logit) {
  __shared__ char As[3][256 * 128];   // 96 KB; LDS[r][b] = A-row byte (b ^ ((r&7)<<4))
  __shared__ char Bs[3][128 * 128];   // 48 KB
  __shared__ int tgt_s[256];

  const int t = threadIdx.x, lane = t & 63, wid = t >> 6;
  const int wr = wid >> 1, wc = wid & 1;

  // XCD-bijective swizzle (6256 % 8 == 0); bx fastest within a chunk so the
  // 16 row-blocks sharing one B panel land on the same XCD.
  const int orig = blockIdx.y * 16 + blockIdx.x;
  const int swz = (orig & 7) * 782 + (orig >> 3);
  const int bx = swz & 15, by = swz >> 4;
  const int row0 = bx * 256, col0 = by * 128;

  if (t < 256) tgt_s[t] = target[row0 + t];

  // staging geometry: per 1 KB chunk q (8 rows x 128 B), lane l -> row q*8+(l>>3),
  // LDS byte-in-row (l&7)*16; global element offset pre-swizzled (rule #21).
  const int rsub = lane >> 3;
  const int kel = ((lane & 7) ^ rsub) << 3;

  auto STAGE = [&](int kt, int buf) {
#pragma unroll
    for (int i = 0; i < 4; ++i) {                      // A: 32 KB, 4 loads/thread
      const int q = wid * 4 + i;
      const int r = q * 8 + rsub;
      const ushort* src = A + (size_t)(row0 + r) * D_ + kt * 64 + kel;
      __builtin_amdgcn_global_load_lds((glob_cv*)src, (lds_v*)(&As[buf][q * 1024]), 16, 0, 0);
    }
#pragma unroll
    for (int i = 0; i < 2; ++i) {                      // B: 16 KB, 2 loads/thread
      const int q = wid * 2 + i;
      const int r = q * 8 + rsub;
      const int gc = col0 + r;
      const ushort* src = Wb + (size_t)(gc < C_ ? gc : 0) * D_ + kt * 64 + kel;
      __builtin_amdgcn_global_load_lds((glob_cv*)src, (lds_v*)(&Bs[buf][q * 1024]), 16, 0, 0);
    }
  };

  f32x4 acc[4][4] = {};

  STAGE(0, 0);
  STAGE(1, 1);

#pragma unroll
  for (int kt = 0; kt < 8; ++kt) {
    if (kt + 2 < 8) STAGE(kt + 2, (kt + 2) % 3);
    if (kt < 6)       { WAITVM(12); }
    else if (kt == 6) { WAITVM(6); }
    else              { WAITVM(0); }
    __builtin_amdgcn_s_barrier();
    __builtin_amdgcn_sched_barrier(0);

    const int buf = kt % 3;
    const char* Ab = As[buf];
    const char* Bb = Bs[buf];
    const int kb0 = (lane >> 4) << 4;
    bf16x8 af[4][2], bfr[4][2];
#pragma unroll
    for (int m = 0; m < 4; ++m) {
      const int r = wr * 64 + m * 16 + (lane & 15);
      const int sw = (r & 7) << 4;
#pragma unroll
      for (int h = 0; h < 2; ++h)
        af[m][h] = *reinterpret_cast<const bf16x8*>(Ab + r * 128 + ((h * 64 + kb0) ^ sw));
    }
#pragma unroll
    for (int n = 0; n < 4; ++n) {
      const int c = wc * 64 + n * 16 + (lane & 15);
      const int sw = (c & 7) << 4;
#pragma unroll
      for (int h = 0; h < 2; ++h)
        bfr[n][h] = *reinterpret_cast<const bf16x8*>(Bb + c * 128 + ((h * 64 + kb0) ^ sw));
    }

    __builtin_amdgcn_s_setprio(1);
#pragma unroll
    for (int h = 0; h < 2; ++h)
#pragma unroll
      for (int m = 0; m < 4; ++m)
#pragma unroll
        for (int n = 0; n < 4; ++n)
          acc[m][n] = __builtin_amdgcn_mfma_f32_16x16x32_bf16(af[m][h], bfr[n][h], acc[m][n], 0, 0, 0);
    __builtin_amdgcn_s_setprio(0);

    __builtin_amdgcn_sched_barrier(0);
    __builtin_amdgcn_s_barrier();   // protect buf[kt%3] from next iter's STAGE(kt+3)
  }

  // full fence before cross-wave tgt_s read (raw s_barrier is not a compiler fence)
  __syncthreads();

  // epilogue: exp-sum per row + target extraction. C/D: col=lane&15, row=(lane>>4)*4+reg
#pragma unroll
  for (int m = 0; m < 4; ++m) {
#pragma unroll
    for (int j = 0; j < 4; ++j) {
      const int lr = wr * 64 + m * 16 + ((lane >> 4) << 2) + j;
      const int grow = row0 + lr;
      const int trow = tgt_s[lr];
      float s = 0.f;
#pragma unroll
      for (int n = 0; n < 4; ++n) {
        const int gcol = col0 + wc * 64 + n * 16 + (lane & 15);
        const float v = acc[m][n][j];
        if (gcol < C_) s += __expf(S_ * v);
        if (gcol == trow) tgt_logit[grow] = v;
      }
      s += __shfl_xor(s, 1); s += __shfl_xor(s, 2);
      s += __shfl_xor(s, 4); s += __shfl_xor(s, 8);
      if ((lane & 15) == 0) atomicAdd(&row_sum[grow], s);
    }
  }
}

// ---------------- 2b) fallback GEMM (round-1 path, fp32 W in-loop convert) ----------------
__global__ __launch_bounds__(256) void gemm_kernel(
    const ushort* __restrict__ A, const float* __restrict__ W,
    const int* __restrict__ target, float* __restrict__ row_sum,
    float* __restrict__ tgt_logit) {
  constexpr int BM = 128, BN = 128, BK = 64;
  __shared__ char As[BM * BK * 2];
  __shared__ char Bs[BN * BK * 2];
  __shared__ int tgt_s[BM];
  const int t = threadIdx.x;
  const int lane = t & 63, wid = t >> 6;
  const int wr = wid >> 1, wc = wid & 1;
  const int row0 = blockIdx.x * BM;
  const int col0 = blockIdx.y * BN;
  if (t < BM) tgt_s[t] = target[row0 + t];
  f32x4 acc[4][4] = {};
  for (int kt = 0; kt < D_ / BK; ++kt) {
    __syncthreads();
#pragma unroll
    for (int i = 0; i < 4; ++i) {
      const int L = i * 4096 + t * 16;
      const int r = L >> 7, kb = L & 127;
      const char* gsrc = reinterpret_cast<const char*>(A) +
                         (size_t)(row0 + r) * (D_ * 2) + kt * (BK * 2) + kb;
      uint4 v = *reinterpret_cast<const uint4*>(gsrc);
      *reinterpret_cast<uint4*>(As + r * 128 + (kb ^ ((r & 7) << 4))) = v;
    }
#pragma unroll
    for (int j = 0; j < 8; ++j) {
      const int flat = j * 256 + t;
      const int c = flat >> 4, kq = flat & 15;
      const int gc = col0 + c;
      float4 v = make_float4(0.f, 0.f, 0.f, 0.f);
      if (gc < C_)
        v = *reinterpret_cast<const float4*>(W + (size_t)gc * D_ + kt * BK + kq * 4);
      ushort4 h;
      h.x = f2bf(v.x); h.y = f2bf(v.y); h.z = f2bf(v.z); h.w = f2bf(v.w);
      const int kb = kq * 8;
      *reinterpret_cast<ushort4*>(Bs + c * 128 + (kb ^ ((c & 7) << 4))) = h;
    }
    __syncthreads();
#pragma unroll
    for (int h = 0; h < 2; ++h) {
      const int kbh = h * 64 + ((lane >> 4) << 4);
      bf16x8 af[4], bfr[4];
#pragma unroll
      for (int m = 0; m < 4; ++m) {
        const int r = wr * 64 + m * 16 + (lane & 15);
        af[m] = *reinterpret_cast<const bf16x8*>(As + r * 128 + (kbh ^ ((r & 7) << 4)));
      }
#pragma unroll
      for (int n = 0; n < 4; ++n) {
        const int c = wc * 64 + n * 16 + (lane & 15);
        bfr[n] = *reinterpret_cast<const bf16x8*>(Bs + c * 128 + (kbh ^ ((c & 7) << 4)));
      }
#pragma unroll
      for (int m = 0; m < 4; ++m)
#pragma unroll
        for (int n = 0; n < 4; ++n)
          acc[m][n] = __builtin_amdgcn_mfma_f32_16x16x32_bf16(af[m], bfr[n], acc[m][n], 0, 0, 0);
    }
  }
#pragma unroll
  for (int m = 0; m < 4; ++m) {
#pragma unroll
    for (int j = 0; j < 4; ++j) {
      const int lr = wr * 64 + m * 16 + ((lane >> 4) << 2) + j;
      const int grow = row0 + lr;
      const int trow = tgt_s[lr];
      float s = 0.f;
#pragma unroll
      for (int n = 0; n < 4; ++n) {
        const int gcol = col0 + wc * 64 + n * 16 + (lane & 15);
        const float v = acc[m][n][j];
        if (gcol < C_) s += __expf(S_ * v);
        if (gcol == trow) tgt_logit[grow] = v;
      }
      s += __shfl_xor(s, 1); s += __shfl_xor(s, 2);
      s += __shfl_xor(s, 4); s += __shfl_xor(s, 8);
      if ((lane & 15) == 0) atomicAdd(&row_sum[grow], s);
    }
  }
}

// ---------------- 3) final arcface loss (multi-block, atomic accumulate) ----------------
__global__ __launch_bounds__(256) void loss_kernel(const float* __restrict__ row_sum,
                                                   const float* __restrict__ tgt_logit,
                                                   float* __restrict__ out) {
  __shared__ float red[4];
  const int i = blockIdx.x * 256 + threadIdx.x;   // 16 blocks x 256 = 4096 rows
  const float tv = tgt_logit[i];
  const float tc = fminf(fmaxf(tv, -1.0f + EPS_), 1.0f - EPS_);
  const float num = S_ * cosf(acosf(tc) + M_);
  const float excl = row_sum[i] - __expf(S_ * tv);
  const float den = __expf(num) + excl;
  float acc = num - logf(den);
#pragma unroll
  for (int m = 1; m < 64; m <<= 1) acc += __shfl_xor(acc, m);
  if ((threadIdx.x & 63) == 0) red[threadIdx.x >> 6] = acc;
  __syncthreads();
  if (threadIdx.x == 0)
    atomicAdd(out, -(red[0] + red[1] + red[2] + red[3]) / (float)N_);
}

extern "C" void kernel_launch(void* const* d_in, const int* in_sizes, int n_in,
                              void* d_out, int out_size, void* d_ws, size_t ws_size,
                              hipStream_t stream) {
  const float* x = (const float*)d_in[0];
  const float* W = (const float*)d_in[1];
  const int* target = (const int*)d_in[2];
  float* out = (float*)d_out;

  float* row_sum = (float*)d_ws;                     // [4096]
  float* tgt_logit = row_sum + N_;                   // [4096]
  ushort* xnb = (ushort*)(row_sum + 2 * N_);         // bf16 [4096][512] = 4 MB
  ushort* Wb = xnb + (size_t)N_ * D_;                // bf16 [50000][512] = 51.2 MB

  const size_t need = 2 * N_ * sizeof(float) + (size_t)N_ * D_ * 2 + (size_t)C_ * D_ * 2;

  hipMemsetAsync(d_ws, 0, 2 * N_ * sizeof(float), stream);
  hipMemsetAsync(d_out, 0, sizeof(float), stream);
  norm_kernel<<<N_ / 4, 256, 0, stream>>>(x, xnb);
  if (ws_size >= need) {
    convw_kernel<<<2048, 256, 0, stream>>>(W, Wb);
    gemm_deep<<<dim3(16, (C_ + 127) / 128), 512, 0, stream>>>(
        xnb, Wb, target, row_sum, tgt_logit);
  } else {
    gemm_kernel<<<dim3(N_ / 128, (C_ + 127) / 128), 256, 0, stream>>>(
        xnb, W, target, row_sum, tgt_logit);
  }
  loss_kernel<<<N_ / 256, 256, 0, stream>>>(row_sum, tgt_logit, out);
}